// Round 3
// baseline (1050.996 us; speedup 1.0000x reference)
//
#include <hip/hip_runtime.h>
#include <hip/hip_bf16.h>

#define NB 2
#define NH 16
#define SEQ 2048
#define HD 64
#define EMB 1024

typedef unsigned short u16;

__device__ __forceinline__ float b2f(u16 u) {
    union { unsigned int i; float f; } v; v.i = ((unsigned int)u) << 16; return v.f;
}
__device__ __forceinline__ u16 f2b(float f) {
    union { float f; unsigned int i; } v; v.f = f;
    unsigned int x = v.i;
    return (u16)((x + 0x7FFFu + ((x >> 16) & 1u)) >> 16);
}

__device__ __forceinline__ void load4f(const u16* p, float* d) {
    ushort4 v = *reinterpret_cast<const ushort4*>(p);
    d[0] = b2f(v.x); d[1] = b2f(v.y); d[2] = b2f(v.z); d[3] = b2f(v.w);
}
__device__ __forceinline__ void load4f(const float* p, float* d) {
    float4 v = *reinterpret_cast<const float4*>(p);
    d[0] = v.x; d[1] = v.y; d[2] = v.z; d[3] = v.w;
}
__device__ __forceinline__ void load4dyn(const void* p, size_t idx, int isbf16, float* d) {
    if (isbf16) load4f((const u16*)p + idx, d);
    else        load4f((const float*)p + idx, d);
}

// flag=1 if d_in tensors are bf16, 0 if fp32. For bf16 unit-scale data ~all
// u16s have exponent in [110,135]; for fp32 viewed as u16 pairs only the hi
// halves do (~55%).
__global__ __launch_bounds__(256)
void detect_dtype_54571854463007(const u16* __restrict__ x, int* __restrict__ flag) {
    __shared__ int cnt;
    if (threadIdx.x == 0) cnt = 0;
    __syncthreads();
    const u16 v = x[threadIdx.x];
    const int e = (v >> 7) & 0xFF;
    if (e >= 110 && e <= 135) atomicAdd(&cnt, 1);
    __syncthreads();
    if (threadIdx.x == 0) *flag = (cnt >= 200) ? 1 : 0;
}

// C = A[M,K] * B[N,K]^T.   B always follows *flagp (input weights).
// A_MODE: 0 = dtype follows *flagp (input tensor), 2 = fixed fp32 (scratch).
// OUT_MODE 0: row-major [M,N], dtype follows *flagp (fp32 when flag=0).
// OUT_MODE 1: bf16 head-split [B,H,S,D] (internal scratch, always bf16).
template<int OUT_MODE, int A_MODE>
__global__ __launch_bounds__(256)
void gemm_bt_54571854463007(const void* __restrict__ A, const void* __restrict__ Bw,
                            void* __restrict__ C, const int* __restrict__ flagp,
                            int M, int N, int K) {
    __shared__ float As[16][64];
    __shared__ float Bs[16][64];
    const int isbf16 = *flagp;
    const int tid = threadIdx.x;
    const int tx = tid & 15, ty = tid >> 4;
    const int m0 = blockIdx.y * 64, n0 = blockIdx.x * 64;
    const int lrow = tid >> 2;          // 0..63
    const int lc4  = (tid & 3) * 4;     // 0,4,8,12
    float acc[4][4] = {};
    for (int k0 = 0; k0 < K; k0 += 16) {
        float t[4];
        if (A_MODE == 0) load4dyn(A, (size_t)(m0 + lrow) * K + k0 + lc4, isbf16, t);
        else             load4f((const float*)A + (size_t)(m0 + lrow) * K + k0 + lc4, t);
        As[lc4 + 0][lrow] = t[0]; As[lc4 + 1][lrow] = t[1];
        As[lc4 + 2][lrow] = t[2]; As[lc4 + 3][lrow] = t[3];
        load4dyn(Bw, (size_t)(n0 + lrow) * K + k0 + lc4, isbf16, t);
        Bs[lc4 + 0][lrow] = t[0]; Bs[lc4 + 1][lrow] = t[1];
        Bs[lc4 + 2][lrow] = t[2]; Bs[lc4 + 3][lrow] = t[3];
        __syncthreads();
#pragma unroll
        for (int k = 0; k < 16; ++k) {
            float4 av = *reinterpret_cast<const float4*>(&As[k][ty * 4]);
            float4 bv = *reinterpret_cast<const float4*>(&Bs[k][tx * 4]);
            float a[4] = {av.x, av.y, av.z, av.w};
            float b[4] = {bv.x, bv.y, bv.z, bv.w};
#pragma unroll
            for (int i = 0; i < 4; ++i)
#pragma unroll
                for (int j = 0; j < 4; ++j)
                    acc[i][j] += a[i] * b[j];
        }
        __syncthreads();
    }
#pragma unroll
    for (int i = 0; i < 4; ++i) {
        const int m = m0 + ty * 4 + i;
#pragma unroll
        for (int j = 0; j < 4; ++j) {
            const int n = n0 + tx * 4 + j;
            if (OUT_MODE == 0) {
                if (isbf16) ((u16*)C)[(size_t)m * N + n] = f2b(acc[i][j]);
                else        ((float*)C)[(size_t)m * N + n] = acc[i][j];
            } else {
                const int b = m >> 11, s = m & (SEQ - 1);
                const int h = n >> 6,  d = n & (HD - 1);
                ((u16*)C)[((((size_t)b * NH + h) * SEQ + s) << 6) + d] = f2b(acc[i][j]);
            }
        }
    }
}

// In-place RoPE on Q and K, layout [B,H,S,D], D=64 (pairs d, d+32).
__global__ __launch_bounds__(256)
void rope_54571854463007(u16* __restrict__ Q, u16* __restrict__ K) {
    const int idx = blockIdx.x * 256 + threadIdx.x;   // NB*NH*SEQ*32 total
    const int i   = idx & 31;
    const int row = idx >> 5;
    const int s   = row & (SEQ - 1);
    const float invf = powf(10000.0f, -(float)i * (1.0f / 32.0f));
    const float ang  = (float)s * invf;
    float sn, cs;
    sincosf(ang, &sn, &cs);
    const size_t off = (size_t)row * HD + i;
    {
        const float x1 = b2f(Q[off]), x2 = b2f(Q[off + 32]);
        Q[off]      = f2b(x1 * cs - x2 * sn);
        Q[off + 32] = f2b(x2 * cs + x1 * sn);
    }
    {
        const float x1 = b2f(K[off]), x2 = b2f(K[off + 32]);
        K[off]      = f2b(x1 * cs - x2 * sn);
        K[off + 32] = f2b(x2 * cs + x1 * sn);
    }
}

// Causal flash attention. Grid (S/64, H, B), block 256.
// Q,K,V: bf16 [B,H,S,D]. AO: fp32 [B,S,H,D].
__global__ __launch_bounds__(256)
void flash_54571854463007(const u16* __restrict__ Q, const u16* __restrict__ Kt,
                          const u16* __restrict__ Vt, float* __restrict__ AO) {
    __shared__ float Qs[64][68];   // [q_row][d]
    __shared__ float KP[64][68];   // phase 1: K transposed [d][key]; phase 2: P [q_row][key]
    __shared__ float Vs[64][68];   // [key][d]
    __shared__ float red[64][16];
    __shared__ float mrow[64], lrow[64], arow[64];
    const int qt = blockIdx.x, h = blockIdx.y, b = blockIdx.z;
    const int tid = threadIdx.x;
    const int tx = tid & 15, ty = tid >> 4;
    const size_t base = ((size_t)b * NH + h) * SEQ * HD;
    const int lr = tid >> 2;           // row within tile, 0..63
    const int lc = (tid & 3) * 16;     // 16 consecutive d per thread
    {
        const u16* src = Q + base + (size_t)(qt * 64 + lr) * HD + lc;
#pragma unroll
        for (int c = 0; c < 16; c += 4) {
            float t[4]; load4f(src + c, t);
            *reinterpret_cast<float4*>(&Qs[lr][lc + c]) = make_float4(t[0], t[1], t[2], t[3]);
        }
    }
    if (tid < 64) { mrow[tid] = -__builtin_inff(); lrow[tid] = 0.0f; }
    float O[4][4] = {};
    for (int kt = 0; kt <= qt; ++kt) {
        __syncthreads();   // previous iteration's KP/Vs/red reads done
        {
            const u16* ksrc = Kt + base + (size_t)(kt * 64 + lr) * HD + lc;
            const u16* vsrc = Vt + base + (size_t)(kt * 64 + lr) * HD + lc;
#pragma unroll
            for (int c = 0; c < 16; c += 4) {
                float t[4];
                load4f(ksrc + c, t);
                KP[lc + c + 0][lr] = t[0]; KP[lc + c + 1][lr] = t[1];
                KP[lc + c + 2][lr] = t[2]; KP[lc + c + 3][lr] = t[3];
                load4f(vsrc + c, t);
                *reinterpret_cast<float4*>(&Vs[lr][lc + c]) = make_float4(t[0], t[1], t[2], t[3]);
            }
        }
        __syncthreads();
        // S tile: s[i][j] = sum_d Q[r][d] * K[key][d],  r=ty*4+i, key=tx*4+j
        float s[4][4] = {};
        for (int kk = 0; kk < 64; kk += 4) {
            float Q4[4][4], K4[4][4];
#pragma unroll
            for (int i = 0; i < 4; ++i) {
                float4 t = *reinterpret_cast<const float4*>(&Qs[ty * 4 + i][kk]);
                Q4[i][0] = t.x; Q4[i][1] = t.y; Q4[i][2] = t.z; Q4[i][3] = t.w;
            }
#pragma unroll
            for (int c = 0; c < 4; ++c) {
                float4 t = *reinterpret_cast<const float4*>(&KP[kk + c][tx * 4]);
                K4[c][0] = t.x; K4[c][1] = t.y; K4[c][2] = t.z; K4[c][3] = t.w;
            }
#pragma unroll
            for (int i = 0; i < 4; ++i)
#pragma unroll
                for (int j = 0; j < 4; ++j)
#pragma unroll
                    for (int c = 0; c < 4; ++c)
                        s[i][j] += Q4[i][c] * K4[c][j];
        }
        const bool diag = (kt == qt);
#pragma unroll
        for (int i = 0; i < 4; ++i) {
            float rm = -__builtin_inff();
#pragma unroll
            for (int j = 0; j < 4; ++j) {
                s[i][j] *= 0.125f;
                if (diag && (tx * 4 + j > ty * 4 + i)) s[i][j] = -__builtin_inff();
                rm = fmaxf(rm, s[i][j]);
            }
            red[ty * 4 + i][tx] = rm;
        }
        __syncthreads();
        if (tid < 64) {
            float mt = red[tid][0];
#pragma unroll
            for (int j = 1; j < 16; ++j) mt = fmaxf(mt, red[tid][j]);
            const float m  = mrow[tid];
            const float mn = fmaxf(m, mt);
            const float a  = __expf(m - mn);
            mrow[tid] = mn; arow[tid] = a; lrow[tid] *= a;
        }
        __syncthreads();
#pragma unroll
        for (int i = 0; i < 4; ++i) {
            const int r = ty * 4 + i;
            const float mn = mrow[r], a = arow[r];
            float rs = 0.0f;
#pragma unroll
            for (int j = 0; j < 4; ++j) {
                const float p = __expf(s[i][j] - mn);
                s[i][j] = p;
                rs += p;
                O[i][j] *= a;
            }
            red[r][tx] = rs;
        }
        // overlay P onto KP (all K^T reads completed before the barriers above)
#pragma unroll
        for (int i = 0; i < 4; ++i)
#pragma unroll
            for (int j = 0; j < 4; ++j)
                KP[ty * 4 + i][tx * 4 + j] = s[i][j];
        __syncthreads();
        if (tid < 64) {
            float l = lrow[tid];
#pragma unroll
            for (int j = 0; j < 16; ++j) l += red[tid][j];
            lrow[tid] = l;
        }
        // O += P * V
        for (int kk = 0; kk < 64; kk += 4) {
            float P4[4][4], V4[4][4];
#pragma unroll
            for (int i = 0; i < 4; ++i) {
                float4 t = *reinterpret_cast<const float4*>(&KP[ty * 4 + i][kk]);
                P4[i][0] = t.x; P4[i][1] = t.y; P4[i][2] = t.z; P4[i][3] = t.w;
            }
#pragma unroll
            for (int c = 0; c < 4; ++c) {
                float4 t = *reinterpret_cast<const float4*>(&Vs[kk + c][tx * 4]);
                V4[c][0] = t.x; V4[c][1] = t.y; V4[c][2] = t.z; V4[c][3] = t.w;
            }
#pragma unroll
            for (int i = 0; i < 4; ++i)
#pragma unroll
                for (int j = 0; j < 4; ++j)
#pragma unroll
                    for (int c = 0; c < 4; ++c)
                        O[i][j] += P4[i][c] * V4[c][j];
        }
    }
    __syncthreads();
#pragma unroll
    for (int i = 0; i < 4; ++i) {
        const int r = ty * 4 + i;
        const float inv = 1.0f / lrow[r];
        const int q = qt * 64 + r;
#pragma unroll
        for (int j = 0; j < 4; ++j)
            AO[(((size_t)b * SEQ + q) * NH + h) * HD + tx * 4 + j] = O[i][j] * inv;
    }
}

extern "C" void kernel_launch(void* const* d_in, const int* in_sizes, int n_in,
                              void* d_out, int out_size, void* d_ws, size_t ws_size,
                              hipStream_t stream) {
    (void)in_sizes; (void)n_in; (void)out_size; (void)ws_size;
    const void* x  = d_in[0];
    const void* Wq = d_in[1];
    const void* Wk = d_in[2];
    const void* Wv = d_in[3];
    const void* Wo = d_in[4];

    char* ws = (char*)d_ws;
    int*   flag = (int*)ws;                                              // 64 B slot
    const size_t qkv_bytes = (size_t)NB * NH * SEQ * HD * sizeof(u16);   // 8 MB each
    u16*   Qb = (u16*)(ws + 64);
    u16*   Kb = (u16*)(ws + 64 + qkv_bytes);
    u16*   Vb = (u16*)(ws + 64 + 2 * qkv_bytes);
    float* AO = (float*)(ws + 64 + 3 * qkv_bytes);                       // 16 MB fp32

    detect_dtype_54571854463007<<<1, 256, 0, stream>>>((const u16*)x, flag);

    const int M = NB * SEQ, N = EMB, K = EMB;
    dim3 gg(N / 64, M / 64);
    gemm_bt_54571854463007<1, 0><<<gg, 256, 0, stream>>>(x, Wq, Qb, flag, M, N, K);
    gemm_bt_54571854463007<1, 0><<<gg, 256, 0, stream>>>(x, Wk, Kb, flag, M, N, K);
    gemm_bt_54571854463007<1, 0><<<gg, 256, 0, stream>>>(x, Wv, Vb, flag, M, N, K);

    const int rope_threads = NB * NH * SEQ * 32;
    rope_54571854463007<<<rope_threads / 256, 256, 0, stream>>>(Qb, Kb);

    flash_54571854463007<<<dim3(SEQ / 64, NH, NB), 256, 0, stream>>>(Qb, Kb, Vb, AO);

    gemm_bt_54571854463007<0, 2><<<gg, 256, 0, stream>>>(AO, Wo, d_out, flag, M, N, K);
}

// Round 4
// 635.889 us; speedup vs baseline: 1.6528x; 1.6528x over previous
//
#include <hip/hip_runtime.h>
#include <hip/hip_bf16.h>

#define NB 2
#define NH 16
#define SEQ 2048
#define HD 64
#define EMB 1024

typedef unsigned short u16;
typedef __attribute__((ext_vector_type(8))) short bf16x8;
typedef __attribute__((ext_vector_type(4))) float f32x4;
typedef __attribute__((ext_vector_type(8))) unsigned short us8;

__device__ __forceinline__ float b2f(u16 u) {
    union { unsigned int i; float f; } v; v.i = ((unsigned int)u) << 16; return v.f;
}
__device__ __forceinline__ u16 f2b(float f) {
    union { float f; unsigned int i; } v; v.f = f;
    unsigned int x = v.i;
    return (u16)((x + 0x7FFFu + ((x >> 16) & 1u)) >> 16);
}

__device__ __forceinline__ void load4f(const u16* p, float* d) {
    ushort4 v = *reinterpret_cast<const ushort4*>(p);
    d[0] = b2f(v.x); d[1] = b2f(v.y); d[2] = b2f(v.z); d[3] = b2f(v.w);
}

// async global->LDS, 16B per lane; LDS dest = wave-uniform base + lane*16
__device__ __forceinline__ void gld16(const u16* g, u16* l) {
    __builtin_amdgcn_global_load_lds((const __attribute__((address_space(1))) void*)g,
                                     (__attribute__((address_space(3))) void*)l, 16, 0, 0);
}

// flag=1 if d_in tensors are bf16, 0 if fp32.
__global__ __launch_bounds__(256)
void detect_dtype_54571854463007(const u16* __restrict__ x, int* __restrict__ flag) {
    __shared__ int cnt;
    if (threadIdx.x == 0) cnt = 0;
    __syncthreads();
    const u16 v = x[threadIdx.x];
    const int e = (v >> 7) & 0xFF;
    if (e >= 110 && e <= 135) atomicAdd(&cnt, 1);
    __syncthreads();
    if (threadIdx.x == 0) *flag = (cnt >= 200) ? 1 : 0;
}

// src (fp32 or bf16 per flag) -> bf16 dst. n multiple of 2048.
__global__ __launch_bounds__(256)
void convert_54571854463007(const void* __restrict__ src, u16* __restrict__ dst,
                            const int* __restrict__ flagp, int n) {
    const int i = (blockIdx.x * 256 + threadIdx.x) * 8;
    if (i >= n) return;
    if (*flagp) {
        *reinterpret_cast<uint4*>(dst + i) =
            *reinterpret_cast<const uint4*>((const u16*)src + i);
    } else {
        const float* s = (const float*)src + i;
        float4 a = *reinterpret_cast<const float4*>(s);
        float4 b = *reinterpret_cast<const float4*>(s + 4);
        us8 v;
        v[0] = f2b(a.x); v[1] = f2b(a.y); v[2] = f2b(a.z); v[3] = f2b(a.w);
        v[4] = f2b(b.x); v[5] = f2b(b.y); v[6] = f2b(b.z); v[7] = f2b(b.w);
        *reinterpret_cast<us8*>(dst + i) = v;
    }
}

// MFMA GEMM: C = A[M,K] * Bw[N,K]^T, A/Bw bf16. 128x128 tile, BK=32, 4 waves.
// OUT_MODE 1: fused QKV epilogue -> bf16 [3][B,H,S,D] at C (N=3072).
// OUT_MODE 0: row-major [M,N], dtype per *flagp (fp32 when flag=0).
template<int OUT_MODE>
__global__ __launch_bounds__(256)
void gemm_mfma_54571854463007(const u16* __restrict__ A, const u16* __restrict__ Bw,
                              void* __restrict__ C, const int* __restrict__ flagp,
                              int M, int N, int K) {
    __shared__ __align__(16) u16 As[128 * 32];
    __shared__ __align__(16) u16 Bs[128 * 32];
    const int tid  = threadIdx.x;
    const int wave = tid >> 6, lane = tid & 63;
    const int quad = lane >> 4, fr = lane & 15;
    const int wr = (wave >> 1) * 64, wc = (wave & 1) * 64;
    const int m0 = blockIdx.y * 128, n0 = blockIdx.x * 128;
    const int r0 = tid >> 2;            // staging row (shot 0)
    const int kc = (tid & 3) * 8;       // staging k-offset (elems)
    const f32x4 zz = {0.f, 0.f, 0.f, 0.f};
    f32x4 acc[4][4];
#pragma unroll
    for (int i = 0; i < 4; ++i)
#pragma unroll
        for (int j = 0; j < 4; ++j) acc[i][j] = zz;

    for (int k0 = 0; k0 < K; k0 += 32) {
        gld16(A  + (size_t)(m0 + r0) * K + k0 + kc,      &As[wave * 512]);
        gld16(A  + (size_t)(m0 + 64 + r0) * K + k0 + kc, &As[2048 + wave * 512]);
        gld16(Bw + (size_t)(n0 + r0) * K + k0 + kc,      &Bs[wave * 512]);
        gld16(Bw + (size_t)(n0 + 64 + r0) * K + k0 + kc, &Bs[2048 + wave * 512]);
        __syncthreads();
        bf16x8 af[4], bfr[4];
#pragma unroll
        for (int mi = 0; mi < 4; ++mi)
            af[mi] = *reinterpret_cast<const bf16x8*>(&As[(wr + mi * 16 + fr) * 32 + quad * 8]);
#pragma unroll
        for (int ni = 0; ni < 4; ++ni)
            bfr[ni] = *reinterpret_cast<const bf16x8*>(&Bs[(wc + ni * 16 + fr) * 32 + quad * 8]);
#pragma unroll
        for (int mi = 0; mi < 4; ++mi)
#pragma unroll
            for (int ni = 0; ni < 4; ++ni)
                acc[mi][ni] = __builtin_amdgcn_mfma_f32_16x16x32_bf16(af[mi], bfr[ni], acc[mi][ni], 0, 0, 0);
        __syncthreads();
    }

    const int isbf16 = (OUT_MODE == 0) ? *flagp : 0;
    const size_t TS = (size_t)NB * NH * SEQ * HD;   // per-tensor elems (QKV)
#pragma unroll
    for (int mi = 0; mi < 4; ++mi)
#pragma unroll
        for (int ni = 0; ni < 4; ++ni)
#pragma unroll
            for (int r = 0; r < 4; ++r) {
                const int m = m0 + wr + mi * 16 + quad * 4 + r;
                const int n = n0 + wc + ni * 16 + fr;
                const float v = acc[mi][ni][r];
                if (OUT_MODE == 1) {
                    const int t = n >> 10, idx = n & 1023;
                    const int h = idx >> 6, d = idx & 63;
                    const int b = m >> 11, s = m & (SEQ - 1);
                    ((u16*)C)[t * TS + ((((size_t)b * NH + h) * SEQ + s) << 6) + d] = f2b(v);
                } else {
                    if (isbf16) ((u16*)C)[(size_t)m * N + n] = f2b(v);
                    else        ((float*)C)[(size_t)m * N + n] = v;
                }
            }
}

// In-place RoPE on Q and K, layout [B,H,S,D], D=64 (pairs d, d+32).
__global__ __launch_bounds__(256)
void rope_54571854463007(u16* __restrict__ Q, u16* __restrict__ K) {
    const int idx = blockIdx.x * 256 + threadIdx.x;   // NB*NH*SEQ*32 total
    const int i   = idx & 31;
    const int row = idx >> 5;
    const int s   = row & (SEQ - 1);
    const float invf = powf(10000.0f, -(float)i * (1.0f / 32.0f));
    const float ang  = (float)s * invf;
    float sn, cs;
    sincosf(ang, &sn, &cs);
    const size_t off = (size_t)row * HD + i;
    {
        const float x1 = b2f(Q[off]), x2 = b2f(Q[off + 32]);
        Q[off]      = f2b(x1 * cs - x2 * sn);
        Q[off + 32] = f2b(x2 * cs + x1 * sn);
    }
    {
        const float x1 = b2f(K[off]), x2 = b2f(K[off + 32]);
        K[off]      = f2b(x1 * cs - x2 * sn);
        K[off + 32] = f2b(x2 * cs + x1 * sn);
    }
}

// Causal flash attention. Grid (S/64, H, B), block 256.
// Q,K,V: bf16 [B,H,S,D]. AO: bf16 [B,S,H,D].
__global__ __launch_bounds__(256)
void flash_54571854463007(const u16* __restrict__ Q, const u16* __restrict__ Kt,
                          const u16* __restrict__ Vt, u16* __restrict__ AO) {
    __shared__ float Qs[64][68];
    __shared__ float KP[64][68];
    __shared__ float Vs[64][68];
    __shared__ float red[64][16];
    __shared__ float mrow[64], lrow[64], arow[64];
    const int qt = blockIdx.x, h = blockIdx.y, b = blockIdx.z;
    const int tid = threadIdx.x;
    const int tx = tid & 15, ty = tid >> 4;
    const size_t base = ((size_t)b * NH + h) * SEQ * HD;
    const int lr = tid >> 2;
    const int lc = (tid & 3) * 16;
    {
        const u16* src = Q + base + (size_t)(qt * 64 + lr) * HD + lc;
#pragma unroll
        for (int c = 0; c < 16; c += 4) {
            float t[4]; load4f(src + c, t);
            *reinterpret_cast<float4*>(&Qs[lr][lc + c]) = make_float4(t[0], t[1], t[2], t[3]);
        }
    }
    if (tid < 64) { mrow[tid] = -__builtin_inff(); lrow[tid] = 0.0f; }
    float O[4][4] = {};
    for (int kt = 0; kt <= qt; ++kt) {
        __syncthreads();
        {
            const u16* ksrc = Kt + base + (size_t)(kt * 64 + lr) * HD + lc;
            const u16* vsrc = Vt + base + (size_t)(kt * 64 + lr) * HD + lc;
#pragma unroll
            for (int c = 0; c < 16; c += 4) {
                float t[4];
                load4f(ksrc + c, t);
                KP[lc + c + 0][lr] = t[0]; KP[lc + c + 1][lr] = t[1];
                KP[lc + c + 2][lr] = t[2]; KP[lc + c + 3][lr] = t[3];
                load4f(vsrc + c, t);
                *reinterpret_cast<float4*>(&Vs[lr][lc + c]) = make_float4(t[0], t[1], t[2], t[3]);
            }
        }
        __syncthreads();
        float s[4][4] = {};
        for (int kk = 0; kk < 64; kk += 4) {
            float Q4[4][4], K4[4][4];
#pragma unroll
            for (int i = 0; i < 4; ++i) {
                float4 t = *reinterpret_cast<const float4*>(&Qs[ty * 4 + i][kk]);
                Q4[i][0] = t.x; Q4[i][1] = t.y; Q4[i][2] = t.z; Q4[i][3] = t.w;
            }
#pragma unroll
            for (int c = 0; c < 4; ++c) {
                float4 t = *reinterpret_cast<const float4*>(&KP[kk + c][tx * 4]);
                K4[c][0] = t.x; K4[c][1] = t.y; K4[c][2] = t.z; K4[c][3] = t.w;
            }
#pragma unroll
            for (int i = 0; i < 4; ++i)
#pragma unroll
                for (int j = 0; j < 4; ++j)
#pragma unroll
                    for (int c = 0; c < 4; ++c)
                        s[i][j] += Q4[i][c] * K4[c][j];
        }
        const bool diag = (kt == qt);
#pragma unroll
        for (int i = 0; i < 4; ++i) {
            float rm = -__builtin_inff();
#pragma unroll
            for (int j = 0; j < 4; ++j) {
                s[i][j] *= 0.125f;
                if (diag && (tx * 4 + j > ty * 4 + i)) s[i][j] = -__builtin_inff();
                rm = fmaxf(rm, s[i][j]);
            }
            red[ty * 4 + i][tx] = rm;
        }
        __syncthreads();
        if (tid < 64) {
            float mt = red[tid][0];
#pragma unroll
            for (int j = 1; j < 16; ++j) mt = fmaxf(mt, red[tid][j]);
            const float m  = mrow[tid];
            const float mn = fmaxf(m, mt);
            const float a  = __expf(m - mn);
            mrow[tid] = mn; arow[tid] = a; lrow[tid] *= a;
        }
        __syncthreads();
#pragma unroll
        for (int i = 0; i < 4; ++i) {
            const int r = ty * 4 + i;
            const float mn = mrow[r], a = arow[r];
            float rs = 0.0f;
#pragma unroll
            for (int j = 0; j < 4; ++j) {
                const float p = __expf(s[i][j] - mn);
                s[i][j] = p;
                rs += p;
                O[i][j] *= a;
            }
            red[r][tx] = rs;
        }
#pragma unroll
        for (int i = 0; i < 4; ++i)
#pragma unroll
            for (int j = 0; j < 4; ++j)
                KP[ty * 4 + i][tx * 4 + j] = s[i][j];
        __syncthreads();
        if (tid < 64) {
            float l = lrow[tid];
#pragma unroll
            for (int j = 0; j < 16; ++j) l += red[tid][j];
            lrow[tid] = l;
        }
        for (int kk = 0; kk < 64; kk += 4) {
            float P4[4][4], V4[4][4];
#pragma unroll
            for (int i = 0; i < 4; ++i) {
                float4 t = *reinterpret_cast<const float4*>(&KP[ty * 4 + i][kk]);
                P4[i][0] = t.x; P4[i][1] = t.y; P4[i][2] = t.z; P4[i][3] = t.w;
            }
#pragma unroll
            for (int c = 0; c < 4; ++c) {
                float4 t = *reinterpret_cast<const float4*>(&Vs[kk + c][tx * 4]);
                V4[c][0] = t.x; V4[c][1] = t.y; V4[c][2] = t.z; V4[c][3] = t.w;
            }
#pragma unroll
            for (int i = 0; i < 4; ++i)
#pragma unroll
                for (int j = 0; j < 4; ++j)
#pragma unroll
                    for (int c = 0; c < 4; ++c)
                        O[i][j] += P4[i][c] * V4[c][j];
        }
    }
    __syncthreads();
#pragma unroll
    for (int i = 0; i < 4; ++i) {
        const int r = ty * 4 + i;
        const float inv = 1.0f / lrow[r];
        const int q = qt * 64 + r;
#pragma unroll
        for (int j = 0; j < 4; ++j)
            AO[(((size_t)b * SEQ + q) * NH + h) * HD + tx * 4 + j] = f2b(O[i][j] * inv);
    }
}

extern "C" void kernel_launch(void* const* d_in, const int* in_sizes, int n_in,
                              void* d_out, int out_size, void* d_ws, size_t ws_size,
                              hipStream_t stream) {
    (void)in_sizes; (void)n_in; (void)out_size; (void)ws_size;
    const void* x  = d_in[0];
    const void* Wq = d_in[1];
    const void* Wk = d_in[2];
    const void* Wv = d_in[3];
    const void* Wo = d_in[4];

    char* ws = (char*)d_ws;
    const size_t MB = 1024 * 1024;
    int* flag = (int*)ws;                                   // 64 B
    u16* xb   = (u16*)(ws + 64);                            // 8 MB  (reused as AO)
    u16* Wqkv = (u16*)(ws + 64 + 8 * MB);                   // 6 MB
    u16* Wob  = (u16*)(ws + 64 + 14 * MB);                  // 2 MB
    u16* Qb   = (u16*)(ws + 64 + 16 * MB);                  // 8 MB
    u16* Kb   = (u16*)(ws + 64 + 24 * MB);                  // 8 MB
    u16* Vb   = (u16*)(ws + 64 + 32 * MB);                  // 8 MB  (total 40 MB + 64)
    u16* AO   = xb;                                         // x dead after QKV GEMM

    detect_dtype_54571854463007<<<1, 256, 0, stream>>>((const u16*)x, flag);

    const int NX = NB * SEQ * EMB;      // 4 M
    const int NW = EMB * EMB;           // 1 M
    convert_54571854463007<<<NX / 2048, 256, 0, stream>>>(x,  xb,            flag, NX);
    convert_54571854463007<<<NW / 2048, 256, 0, stream>>>(Wq, Wqkv,          flag, NW);
    convert_54571854463007<<<NW / 2048, 256, 0, stream>>>(Wk, Wqkv + NW,     flag, NW);
    convert_54571854463007<<<NW / 2048, 256, 0, stream>>>(Wv, Wqkv + 2 * NW, flag, NW);
    convert_54571854463007<<<NW / 2048, 256, 0, stream>>>(Wo, Wob,           flag, NW);

    const int M = NB * SEQ;
    // Fused QKV: N = 3*EMB = 3072
    gemm_mfma_54571854463007<1><<<dim3(3 * EMB / 128, M / 128), 256, 0, stream>>>(
        xb, Wqkv, Qb, flag, M, 3 * EMB, EMB);

    const int rope_threads = NB * NH * SEQ * 32;
    rope_54571854463007<<<rope_threads / 256, 256, 0, stream>>>(Qb, Kb);

    flash_54571854463007<<<dim3(SEQ / 64, NH, NB), 256, 0, stream>>>(Qb, Kb, Vb, AO);

    gemm_mfma_54571854463007<0><<<dim3(EMB / 128, M / 128), 256, 0, stream>>>(
        AO, Wob, d_out, flag, M, EMB, EMB);
}

// Round 5
// 307.892 us; speedup vs baseline: 3.4135x; 2.0653x over previous
//
#include <hip/hip_runtime.h>
#include <hip/hip_bf16.h>

#define NB 2
#define NH 16
#define SEQ 2048
#define HD 64
#define EMB 1024

typedef unsigned short u16;
typedef __attribute__((ext_vector_type(8))) short bf16x8;
typedef __attribute__((ext_vector_type(4))) float f32x4;
typedef __attribute__((ext_vector_type(8))) unsigned short us8;

__device__ __forceinline__ float b2f(u16 u) {
    union { unsigned int i; float f; } v; v.i = ((unsigned int)u) << 16; return v.f;
}
__device__ __forceinline__ u16 f2b(float f) {
    union { float f; unsigned int i; } v; v.f = f;
    unsigned int x = v.i;
    return (u16)((x + 0x7FFFu + ((x >> 16) & 1u)) >> 16);
}

// async global->LDS, 16B per lane; LDS dest = wave-uniform base + lane*16
__device__ __forceinline__ void gld16(const u16* g, u16* l) {
    __builtin_amdgcn_global_load_lds((const __attribute__((address_space(1))) void*)g,
                                     (__attribute__((address_space(3))) void*)l, 16, 0, 0);
}

// flag=1 if d_in tensors are bf16, 0 if fp32.
__global__ __launch_bounds__(256)
void detect_dtype_54571854463007(const u16* __restrict__ x, int* __restrict__ flag) {
    __shared__ int cnt;
    if (threadIdx.x == 0) cnt = 0;
    __syncthreads();
    const u16 v = x[threadIdx.x];
    const int e = (v >> 7) & 0xFF;
    if (e >= 110 && e <= 135) atomicAdd(&cnt, 1);
    __syncthreads();
    if (threadIdx.x == 0) *flag = (cnt >= 200) ? 1 : 0;
}

// src (fp32 or bf16 per flag) -> bf16 dst. n multiple of 2048.
__global__ __launch_bounds__(256)
void convert_54571854463007(const void* __restrict__ src, u16* __restrict__ dst,
                            const int* __restrict__ flagp, int n) {
    const int i = (blockIdx.x * 256 + threadIdx.x) * 8;
    if (i >= n) return;
    if (*flagp) {
        *reinterpret_cast<uint4*>(dst + i) =
            *reinterpret_cast<const uint4*>((const u16*)src + i);
    } else {
        const float* s = (const float*)src + i;
        float4 a = *reinterpret_cast<const float4*>(s);
        float4 b = *reinterpret_cast<const float4*>(s + 4);
        us8 v;
        v[0] = f2b(a.x); v[1] = f2b(a.y); v[2] = f2b(a.z); v[3] = f2b(a.w);
        v[4] = f2b(b.x); v[5] = f2b(b.y); v[6] = f2b(b.z); v[7] = f2b(b.w);
        *reinterpret_cast<us8*>(dst + i) = v;
    }
}

// MFMA GEMM: C = A[M,K] * Bw[N,K]^T, A/Bw bf16. 128x128 tile, BK=32, 4 waves.
// OUT_MODE 1: fused QKV epilogue -> bf16 [3][B,H,S,D] at C (N=3072).
// OUT_MODE 0: row-major [M,N], dtype per *flagp (fp32 when flag=0).
template<int OUT_MODE>
__global__ __launch_bounds__(256)
void gemm_mfma_54571854463007(const u16* __restrict__ A, const u16* __restrict__ Bw,
                              void* __restrict__ C, const int* __restrict__ flagp,
                              int M, int N, int K) {
    __shared__ __align__(16) u16 As[128 * 32];
    __shared__ __align__(16) u16 Bs[128 * 32];
    const int tid  = threadIdx.x;
    const int wave = tid >> 6, lane = tid & 63;
    const int quad = lane >> 4, fr = lane & 15;
    const int wr = (wave >> 1) * 64, wc = (wave & 1) * 64;
    const int m0 = blockIdx.y * 128, n0 = blockIdx.x * 128;
    const int r0 = tid >> 2;
    const int kc = (tid & 3) * 8;
    const f32x4 zz = {0.f, 0.f, 0.f, 0.f};
    f32x4 acc[4][4];
#pragma unroll
    for (int i = 0; i < 4; ++i)
#pragma unroll
        for (int j = 0; j < 4; ++j) acc[i][j] = zz;

    for (int k0 = 0; k0 < K; k0 += 32) {
        gld16(A  + (size_t)(m0 + r0) * K + k0 + kc,      &As[wave * 512]);
        gld16(A  + (size_t)(m0 + 64 + r0) * K + k0 + kc, &As[2048 + wave * 512]);
        gld16(Bw + (size_t)(n0 + r0) * K + k0 + kc,      &Bs[wave * 512]);
        gld16(Bw + (size_t)(n0 + 64 + r0) * K + k0 + kc, &Bs[2048 + wave * 512]);
        __syncthreads();
        bf16x8 af[4], bfr[4];
#pragma unroll
        for (int mi = 0; mi < 4; ++mi)
            af[mi] = *reinterpret_cast<const bf16x8*>(&As[(wr + mi * 16 + fr) * 32 + quad * 8]);
#pragma unroll
        for (int ni = 0; ni < 4; ++ni)
            bfr[ni] = *reinterpret_cast<const bf16x8*>(&Bs[(wc + ni * 16 + fr) * 32 + quad * 8]);
#pragma unroll
        for (int mi = 0; mi < 4; ++mi)
#pragma unroll
            for (int ni = 0; ni < 4; ++ni)
                acc[mi][ni] = __builtin_amdgcn_mfma_f32_16x16x32_bf16(af[mi], bfr[ni], acc[mi][ni], 0, 0, 0);
        __syncthreads();
    }

    const int isbf16 = (OUT_MODE == 0) ? *flagp : 0;
    const size_t TS = (size_t)NB * NH * SEQ * HD;
#pragma unroll
    for (int mi = 0; mi < 4; ++mi)
#pragma unroll
        for (int ni = 0; ni < 4; ++ni)
#pragma unroll
            for (int r = 0; r < 4; ++r) {
                const int m = m0 + wr + mi * 16 + quad * 4 + r;
                const int n = n0 + wc + ni * 16 + fr;
                const float v = acc[mi][ni][r];
                if (OUT_MODE == 1) {
                    const int t = n >> 10, idx = n & 1023;
                    const int h = idx >> 6, d = idx & 63;
                    const int b = m >> 11, s = m & (SEQ - 1);
                    ((u16*)C)[t * TS + ((((size_t)b * NH + h) * SEQ + s) << 6) + d] = f2b(v);
                } else {
                    if (isbf16) ((u16*)C)[(size_t)m * N + n] = f2b(v);
                    else        ((float*)C)[(size_t)m * N + n] = v;
                }
            }
}

// In-place RoPE on Q and K, layout [B,H,S,D], D=64 (pairs d, d+32).
__global__ __launch_bounds__(256)
void rope_54571854463007(u16* __restrict__ Q, u16* __restrict__ K) {
    const int idx = blockIdx.x * 256 + threadIdx.x;
    const int i   = idx & 31;
    const int row = idx >> 5;
    const int s   = row & (SEQ - 1);
    const float invf = powf(10000.0f, -(float)i * (1.0f / 32.0f));
    const float ang  = (float)s * invf;
    float sn, cs;
    sincosf(ang, &sn, &cs);
    const size_t off = (size_t)row * HD + i;
    {
        const float x1 = b2f(Q[off]), x2 = b2f(Q[off + 32]);
        Q[off]      = f2b(x1 * cs - x2 * sn);
        Q[off + 32] = f2b(x2 * cs + x1 * sn);
    }
    {
        const float x1 = b2f(K[off]), x2 = b2f(K[off + 32]);
        K[off]      = f2b(x1 * cs - x2 * sn);
        K[off + 32] = f2b(x2 * cs + x1 * sn);
    }
}

// MFMA causal flash attention. Grid (32, NH, NB), block 256 (4 waves x 16 q-rows).
// Q,K,V bf16 [B,H,S,D]; AO bf16 [B,S,H,D] (= [B,S,E] row-major).
// Per kt-tile: stage K natural [2][64][32] via global_load_lds, V transposed
// [2][64 d][40] via registers. QK^T and PV on mfma_f32_16x16x32_bf16; P
// round-trips LDS (C-layout -> A-layout, m120-verified). Softmax state in
// regs (4 rows/lane, replicated over fr lanes).
__global__ __launch_bounds__(256)
void flash_54571854463007(const u16* __restrict__ Q, const u16* __restrict__ K,
                          const u16* __restrict__ V, u16* __restrict__ AO) {
    __shared__ __align__(16) u16 Qs[4096];   // [2][64][32]
    __shared__ __align__(16) u16 Ks[4096];   // [2][64][32]
    __shared__ __align__(16) u16 Vt[5120];   // [2][64 d][40] (stride-40 pad)
    __shared__ __align__(16) u16 Ps[5120];   // [2][64 q][40]
    const int tid  = threadIdx.x;
    const int w    = tid >> 6, lane = tid & 63;
    const int quad = lane >> 4, fr = lane & 15;
    const int bix  = blockIdx.x;
    const int qt   = (bix & 1) ? (31 - (bix >> 1)) : (bix >> 1);   // work-balance pairing
    const int h = blockIdx.y, b = blockIdx.z;
    const size_t base = ((size_t)b * NH + h) * SEQ * HD;
    const int r0 = tid >> 2, kc8 = (tid & 3) * 8;

    // stage Q once
    gld16(Q + base + (size_t)(qt * 64 + r0) * HD + kc8,      &Qs[w * 512]);
    gld16(Q + base + (size_t)(qt * 64 + r0) * HD + 32 + kc8, &Qs[2048 + w * 512]);

    float m_[4], l_[4];
#pragma unroll
    for (int r = 0; r < 4; ++r) { m_[r] = -__builtin_inff(); l_[r] = 0.f; }
    const f32x4 zz = {0.f, 0.f, 0.f, 0.f};
    f32x4 oacc[4];
#pragma unroll
    for (int nt = 0; nt < 4; ++nt) oacc[nt] = zz;

    for (int kt = 0; kt <= qt; ++kt) {
        __syncthreads();   // prev-iter LDS reads done; Q DMA drained (iter 0)
        gld16(K + base + (size_t)(kt * 64 + r0) * HD + kc8,      &Ks[w * 512]);
        gld16(K + base + (size_t)(kt * 64 + r0) * HD + 32 + kc8, &Ks[2048 + w * 512]);
        {
            // V transpose: lane = key, wave w covers d = w*16 .. w*16+15
            const u16* vsrc = V + base + (size_t)(kt * 64 + lane) * HD + w * 16;
            us8 v0 = *reinterpret_cast<const us8*>(vsrc);
            us8 v1 = *reinterpret_cast<const us8*>(vsrc + 8);
            const int kcv = (lane >> 5) * 2560, kk = lane & 31;
#pragma unroll
            for (int j = 0; j < 8; ++j) {
                Vt[kcv + (w * 16 + j) * 40 + kk]     = v0[j];
                Vt[kcv + (w * 16 + 8 + j) * 40 + kk] = v1[j];
            }
        }
        __syncthreads();
        // QK^T : S[q][key], q rows w*16..+15
        bf16x8 aq0 = *reinterpret_cast<const bf16x8*>(&Qs[(w * 16 + fr) * 32 + quad * 8]);
        bf16x8 aq1 = *reinterpret_cast<const bf16x8*>(&Qs[2048 + (w * 16 + fr) * 32 + quad * 8]);
        f32x4 sa[4];
#pragma unroll
        for (int nt = 0; nt < 4; ++nt) {
            bf16x8 bk0 = *reinterpret_cast<const bf16x8*>(&Ks[(nt * 16 + fr) * 32 + quad * 8]);
            bf16x8 bk1 = *reinterpret_cast<const bf16x8*>(&Ks[2048 + (nt * 16 + fr) * 32 + quad * 8]);
            sa[nt] = __builtin_amdgcn_mfma_f32_16x16x32_bf16(aq0, bk0, zz, 0, 0, 0);
            sa[nt] = __builtin_amdgcn_mfma_f32_16x16x32_bf16(aq1, bk1, sa[nt], 0, 0, 0);
        }
        // scale + causal mask (C-layout: row=quad*4+r, col=fr)
        const bool diag = (kt == qt);
#pragma unroll
        for (int nt = 0; nt < 4; ++nt)
#pragma unroll
            for (int r = 0; r < 4; ++r) {
                float s = sa[nt][r] * 0.125f;
                if (diag && (nt * 16 + fr > w * 16 + quad * 4 + r)) s = -__builtin_inff();
                sa[nt][r] = s;
            }
        // online softmax, P -> LDS (bf16)
#pragma unroll
        for (int r = 0; r < 4; ++r) {
            float mt = fmaxf(fmaxf(sa[0][r], sa[1][r]), fmaxf(sa[2][r], sa[3][r]));
            mt = fmaxf(mt, __shfl_xor(mt, 1));
            mt = fmaxf(mt, __shfl_xor(mt, 2));
            mt = fmaxf(mt, __shfl_xor(mt, 4));
            mt = fmaxf(mt, __shfl_xor(mt, 8));
            const float mn = fmaxf(m_[r], mt);
            const float al = __expf(m_[r] - mn);
            m_[r] = mn;
            float rs = 0.f;
            const int prow = (w * 16 + quad * 4 + r) * 40 + fr;
#pragma unroll
            for (int nt = 0; nt < 4; ++nt) {
                const float p = __expf(sa[nt][r] - mn);
                rs += p;
                Ps[(nt >> 1) * 2560 + prow + (nt & 1) * 16] = f2b(p);
                oacc[nt][r] *= al;
            }
            rs += __shfl_xor(rs, 1);
            rs += __shfl_xor(rs, 2);
            rs += __shfl_xor(rs, 4);
            rs += __shfl_xor(rs, 8);
            l_[r] = l_[r] * al + rs;
        }
        // PV : O[q][d] += P[q][key] * V[key][d]   (same-wave P rows, no barrier)
        bf16x8 ap0 = *reinterpret_cast<const bf16x8*>(&Ps[(w * 16 + fr) * 40 + quad * 8]);
        bf16x8 ap1 = *reinterpret_cast<const bf16x8*>(&Ps[2560 + (w * 16 + fr) * 40 + quad * 8]);
#pragma unroll
        for (int nt = 0; nt < 4; ++nt) {
            bf16x8 bv0 = *reinterpret_cast<const bf16x8*>(&Vt[(nt * 16 + fr) * 40 + quad * 8]);
            bf16x8 bv1 = *reinterpret_cast<const bf16x8*>(&Vt[2560 + (nt * 16 + fr) * 40 + quad * 8]);
            oacc[nt] = __builtin_amdgcn_mfma_f32_16x16x32_bf16(ap0, bv0, oacc[nt], 0, 0, 0);
            oacc[nt] = __builtin_amdgcn_mfma_f32_16x16x32_bf16(ap1, bv1, oacc[nt], 0, 0, 0);
        }
    }
    // epilogue: AO[b][q][h][d]
#pragma unroll
    for (int r = 0; r < 4; ++r) {
        const float inv = 1.0f / l_[r];
        const int q = qt * 64 + w * 16 + quad * 4 + r;
#pragma unroll
        for (int nt = 0; nt < 4; ++nt)
            AO[(((size_t)b * SEQ + q) * NH + h) * HD + nt * 16 + fr] = f2b(oacc[nt][r] * inv);
    }
}

extern "C" void kernel_launch(void* const* d_in, const int* in_sizes, int n_in,
                              void* d_out, int out_size, void* d_ws, size_t ws_size,
                              hipStream_t stream) {
    (void)in_sizes; (void)n_in; (void)out_size; (void)ws_size;
    const void* x  = d_in[0];
    const void* Wq = d_in[1];
    const void* Wk = d_in[2];
    const void* Wv = d_in[3];
    const void* Wo = d_in[4];

    char* ws = (char*)d_ws;
    const size_t MB = 1024 * 1024;
    int* flag = (int*)ws;                                   // 64 B
    u16* xb   = (u16*)(ws + 64);                            // 8 MB (reused as AO)
    u16* Wqkv = (u16*)(ws + 64 + 8 * MB);                   // 6 MB
    u16* Wob  = (u16*)(ws + 64 + 14 * MB);                  // 2 MB
    u16* Qb   = (u16*)(ws + 64 + 16 * MB);                  // 8 MB
    u16* Kb   = (u16*)(ws + 64 + 24 * MB);                  // 8 MB
    u16* Vb   = (u16*)(ws + 64 + 32 * MB);                  // 8 MB (total 40 MB + 64)
    u16* AO   = xb;                                         // x dead after QKV GEMM

    detect_dtype_54571854463007<<<1, 256, 0, stream>>>((const u16*)x, flag);

    const int NX = NB * SEQ * EMB;
    const int NW = EMB * EMB;
    convert_54571854463007<<<NX / 2048, 256, 0, stream>>>(x,  xb,            flag, NX);
    convert_54571854463007<<<NW / 2048, 256, 0, stream>>>(Wq, Wqkv,          flag, NW);
    convert_54571854463007<<<NW / 2048, 256, 0, stream>>>(Wk, Wqkv + NW,     flag, NW);
    convert_54571854463007<<<NW / 2048, 256, 0, stream>>>(Wv, Wqkv + 2 * NW, flag, NW);
    convert_54571854463007<<<NW / 2048, 256, 0, stream>>>(Wo, Wob,           flag, NW);

    const int M = NB * SEQ;
    gemm_mfma_54571854463007<1><<<dim3(3 * EMB / 128, M / 128), 256, 0, stream>>>(
        xb, Wqkv, Qb, flag, M, 3 * EMB, EMB);

    const int rope_threads = NB * NH * SEQ * 32;
    rope_54571854463007<<<rope_threads / 256, 256, 0, stream>>>(Qb, Kb);

    flash_54571854463007<<<dim3(32, NH, NB), 256, 0, stream>>>(Qb, Kb, Vb, AO);

    gemm_mfma_54571854463007<0><<<dim3(EMB / 128, M / 128), 256, 0, stream>>>(
        AO, Wob, d_out, flag, M, EMB, EMB);
}

// Round 6
// 252.980 us; speedup vs baseline: 4.1545x; 1.2171x over previous
//
#include <hip/hip_runtime.h>
#include <hip/hip_bf16.h>

#define NB 2
#define NH 16
#define SEQ 2048
#define HD 64
#define EMB 1024

typedef unsigned short u16;
typedef unsigned int u32;
typedef __attribute__((ext_vector_type(8))) short bf16x8;
typedef __attribute__((ext_vector_type(4))) float f32x4;
typedef __attribute__((ext_vector_type(8))) unsigned short us8;

__device__ __forceinline__ float b2f(u16 u) {
    union { unsigned int i; float f; } v; v.i = ((unsigned int)u) << 16; return v.f;
}
__device__ __forceinline__ u16 f2b(float f) {
    union { float f; unsigned int i; } v; v.f = f;
    unsigned int x = v.i;
    return (u16)((x + 0x7FFFu + ((x >> 16) & 1u)) >> 16);
}

// async global->LDS, 16B per lane; LDS dest = wave-uniform base + lane*16
__device__ __forceinline__ void gld16(const u16* g, u16* l) {
    __builtin_amdgcn_global_load_lds((const __attribute__((address_space(1))) void*)g,
                                     (__attribute__((address_space(3))) void*)l, 16, 0, 0);
}

// flag=1 if d_in tensors are bf16, 0 if fp32.
__global__ __launch_bounds__(256)
void detect_dtype_54571854463007(const u16* __restrict__ x, int* __restrict__ flag) {
    __shared__ int cnt;
    if (threadIdx.x == 0) cnt = 0;
    __syncthreads();
    const u16 v = x[threadIdx.x];
    const int e = (v >> 7) & 0xFF;
    if (e >= 110 && e <= 135) atomicAdd(&cnt, 1);
    __syncthreads();
    if (threadIdx.x == 0) *flag = (cnt >= 200) ? 1 : 0;
}

// src (fp32 or bf16 per flag) -> bf16 dst. n multiple of 2048.
__global__ __launch_bounds__(256)
void convert_54571854463007(const void* __restrict__ src, u16* __restrict__ dst,
                            const int* __restrict__ flagp, int n) {
    const int i = (blockIdx.x * 256 + threadIdx.x) * 8;
    if (i >= n) return;
    if (*flagp) {
        *reinterpret_cast<uint4*>(dst + i) =
            *reinterpret_cast<const uint4*>((const u16*)src + i);
    } else {
        const float* s = (const float*)src + i;
        float4 a = *reinterpret_cast<const float4*>(s);
        float4 b = *reinterpret_cast<const float4*>(s + 4);
        us8 v;
        v[0] = f2b(a.x); v[1] = f2b(a.y); v[2] = f2b(a.z); v[3] = f2b(a.w);
        v[4] = f2b(b.x); v[5] = f2b(b.y); v[6] = f2b(b.z); v[7] = f2b(b.w);
        *reinterpret_cast<us8*>(dst + i) = v;
    }
}

// MFMA GEMM: C = A[M,K] * Bw[N,K]^T, A/Bw bf16. 128x128 tile, BK=32, 4 waves.
// OUT_MODE 1: fused QKV epilogue -> bf16 [3][B,H,S,D] at C (N=3072).
// OUT_MODE 0: row-major [M,N], dtype per *flagp (fp32 when flag=0).
template<int OUT_MODE>
__global__ __launch_bounds__(256)
void gemm_mfma_54571854463007(const u16* __restrict__ A, const u16* __restrict__ Bw,
                              void* __restrict__ C, const int* __restrict__ flagp,
                              int M, int N, int K) {
    __shared__ __align__(16) u16 As[128 * 32];
    __shared__ __align__(16) u16 Bs[128 * 32];
    const int tid  = threadIdx.x;
    const int wave = tid >> 6, lane = tid & 63;
    const int quad = lane >> 4, fr = lane & 15;
    const int wr = (wave >> 1) * 64, wc = (wave & 1) * 64;
    const int m0 = blockIdx.y * 128, n0 = blockIdx.x * 128;
    const int r0 = tid >> 2;
    const int kc = (tid & 3) * 8;
    const f32x4 zz = {0.f, 0.f, 0.f, 0.f};
    f32x4 acc[4][4];
#pragma unroll
    for (int i = 0; i < 4; ++i)
#pragma unroll
        for (int j = 0; j < 4; ++j) acc[i][j] = zz;

    for (int k0 = 0; k0 < K; k0 += 32) {
        gld16(A  + (size_t)(m0 + r0) * K + k0 + kc,      &As[wave * 512]);
        gld16(A  + (size_t)(m0 + 64 + r0) * K + k0 + kc, &As[2048 + wave * 512]);
        gld16(Bw + (size_t)(n0 + r0) * K + k0 + kc,      &Bs[wave * 512]);
        gld16(Bw + (size_t)(n0 + 64 + r0) * K + k0 + kc, &Bs[2048 + wave * 512]);
        __syncthreads();
        bf16x8 af[4], bfr[4];
#pragma unroll
        for (int mi = 0; mi < 4; ++mi)
            af[mi] = *reinterpret_cast<const bf16x8*>(&As[(wr + mi * 16 + fr) * 32 + quad * 8]);
#pragma unroll
        for (int ni = 0; ni < 4; ++ni)
            bfr[ni] = *reinterpret_cast<const bf16x8*>(&Bs[(wc + ni * 16 + fr) * 32 + quad * 8]);
#pragma unroll
        for (int mi = 0; mi < 4; ++mi)
#pragma unroll
            for (int ni = 0; ni < 4; ++ni)
                acc[mi][ni] = __builtin_amdgcn_mfma_f32_16x16x32_bf16(af[mi], bfr[ni], acc[mi][ni], 0, 0, 0);
        __syncthreads();
    }

    const int isbf16 = (OUT_MODE == 0) ? *flagp : 0;
    const size_t TS = (size_t)NB * NH * SEQ * HD;
#pragma unroll
    for (int mi = 0; mi < 4; ++mi)
#pragma unroll
        for (int ni = 0; ni < 4; ++ni)
#pragma unroll
            for (int r = 0; r < 4; ++r) {
                const int m = m0 + wr + mi * 16 + quad * 4 + r;
                const int n = n0 + wc + ni * 16 + fr;
                const float v = acc[mi][ni][r];
                if (OUT_MODE == 1) {
                    const int t = n >> 10, idx = n & 1023;
                    const int h = idx >> 6, d = idx & 63;
                    const int b = m >> 11, s = m & (SEQ - 1);
                    ((u16*)C)[t * TS + ((((size_t)b * NH + h) * SEQ + s) << 6) + d] = f2b(v);
                } else {
                    if (isbf16) ((u16*)C)[(size_t)m * N + n] = f2b(v);
                    else        ((float*)C)[(size_t)m * N + n] = v;
                }
            }
}

// In-place RoPE on Q and K, layout [B,H,S,D], D=64 (pairs d, d+32).
__global__ __launch_bounds__(256)
void rope_54571854463007(u16* __restrict__ Q, u16* __restrict__ K) {
    const int idx = blockIdx.x * 256 + threadIdx.x;
    const int i   = idx & 31;
    const int row = idx >> 5;
    const int s   = row & (SEQ - 1);
    const float invf = powf(10000.0f, -(float)i * (1.0f / 32.0f));
    const float ang  = (float)s * invf;
    float sn, cs;
    sincosf(ang, &sn, &cs);
    const size_t off = (size_t)row * HD + i;
    {
        const float x1 = b2f(Q[off]), x2 = b2f(Q[off + 32]);
        Q[off]      = f2b(x1 * cs - x2 * sn);
        Q[off + 32] = f2b(x2 * cs + x1 * sn);
    }
    {
        const float x1 = b2f(K[off]), x2 = b2f(K[off + 32]);
        K[off]      = f2b(x1 * cs - x2 * sn);
        K[off + 32] = f2b(x2 * cs + x1 * sn);
    }
}

// MFMA causal flash attention, balanced + pipelined.
// Grid (16, NH, NB), block 256 (4 waves). Each block does q-tile qA=bix then
// qB=31-bix: exactly 33 kt-iterations regardless of bix -> zero CU imbalance.
// Per iteration (single barrier): commit prefetched V regs -> Vt[buf]; barrier
// (drains K/Q global_load_lds DMA); issue K(j+1) DMA + V(j+1) reg loads;
// QK^T (mfma 16x16x32 bf16) -> softmax (reg, shfl reductions) -> P via LDS
// (same-wave rows, no barrier) -> PV mfma.
__global__ __launch_bounds__(256)
void flash_54571854463007(const u16* __restrict__ Q, const u16* __restrict__ K,
                          const u16* __restrict__ V, u16* __restrict__ AO) {
    __shared__ __align__(16) u16 Qs[2][4096];   // [phase][2 kchunk][64 q][32]
    __shared__ __align__(16) u16 Ks[2][4096];   // [buf][2 kchunk][64 key][32]
    __shared__ __align__(16) u16 Vt[2][5120];   // [buf][2 keyhalf][64 d][40]
    __shared__ __align__(16) u16 Ps[5120];      //       [2 keyhalf][64 q][40]
    const int tid  = threadIdx.x;
    const int w    = tid >> 6, lane = tid & 63;
    const int quad = lane >> 4, fr = lane & 15;
    const int qA = blockIdx.x;          // 0..15
    const int qB = 31 - qA;             // 16..31
    const int h = blockIdx.y, b = blockIdx.z;
    const size_t base = ((size_t)b * NH + h) * SEQ * HD;
    const int r0 = tid >> 2, kc8 = (tid & 3) * 8;
    // V staging decomposition: lane covers keys {key2,key2+1} x 8 d
    const int key2 = (tid & 31) * 2;
    const int d8   = ((tid >> 5) & 7) * 8;
    const int kcv  = (key2 >> 5) * 2560, kk = key2 & 31;
    const int total = 33;

    // prolog: Q(A), K(0) DMA; V(0) regs
    gld16(Q + base + (size_t)(qA * 64 + r0) * HD + kc8,      &Qs[0][w * 512]);
    gld16(Q + base + (size_t)(qA * 64 + r0) * HD + 32 + kc8, &Qs[0][2048 + w * 512]);
    gld16(K + base + (size_t)r0 * HD + kc8,                  &Ks[0][w * 512]);
    gld16(K + base + (size_t)r0 * HD + 32 + kc8,             &Ks[0][2048 + w * 512]);
    us8 vc0, vc1;
    {
        const u16* vs = V + base + (size_t)key2 * HD + d8;
        vc0 = *reinterpret_cast<const us8*>(vs);
        vc1 = *reinterpret_cast<const us8*>(vs + HD);
    }

    float m_[4], l_[4];
#pragma unroll
    for (int r = 0; r < 4; ++r) { m_[r] = -__builtin_inff(); l_[r] = 0.f; }
    const f32x4 zz = {0.f, 0.f, 0.f, 0.f};
    f32x4 oacc[4];
#pragma unroll
    for (int nt = 0; nt < 4; ++nt) oacc[nt] = zz;
    bf16x8 aq0, aq1;

    for (int j = 0; j < total; ++j) {
        const int buf   = j & 1;
        const int phase = (j > qA) ? 1 : 0;
        const int qtile = phase ? qB : qA;
        const int kt    = phase ? (j - qA - 1) : j;
        // commit V(j): packed b32 stores (keys key2,key2+1 adjacent in row d)
#pragma unroll
        for (int jj = 0; jj < 8; ++jj) {
            const u32 pk = ((u32)(u16)vc1[jj] << 16) | (u32)(u16)vc0[jj];
            *reinterpret_cast<u32*>(&Vt[buf][kcv + (d8 + jj) * 40 + kk]) = pk;
        }
        __syncthreads();   // K(j)/Q DMA drained; Vt[buf] visible; buf^1 readers done
        // prefetch j+1
        if (j + 1 < total) {
            const int nkt = (j + 1 > qA) ? (j - qA) : (j + 1);
            gld16(K + base + (size_t)(nkt * 64 + r0) * HD + kc8,      &Ks[buf ^ 1][w * 512]);
            gld16(K + base + (size_t)(nkt * 64 + r0) * HD + 32 + kc8, &Ks[buf ^ 1][2048 + w * 512]);
            const u16* vs = V + base + (size_t)(nkt * 64 + key2) * HD + d8;
            vc0 = *reinterpret_cast<const us8*>(vs);
            vc1 = *reinterpret_cast<const us8*>(vs + HD);
            if (j == qA) {
                gld16(Q + base + (size_t)(qB * 64 + r0) * HD + kc8,      &Qs[1][w * 512]);
                gld16(Q + base + (size_t)(qB * 64 + r0) * HD + 32 + kc8, &Qs[1][2048 + w * 512]);
            }
        }
        // Q fragments once per phase
        if (j == 0 || j == qA + 1) {
            aq0 = *reinterpret_cast<const bf16x8*>(&Qs[phase][(w * 16 + fr) * 32 + quad * 8]);
            aq1 = *reinterpret_cast<const bf16x8*>(&Qs[phase][2048 + (w * 16 + fr) * 32 + quad * 8]);
        }
        // QK^T: q rows w*16..+15
        f32x4 sa[4];
#pragma unroll
        for (int nt = 0; nt < 4; ++nt) {
            bf16x8 bk0 = *reinterpret_cast<const bf16x8*>(&Ks[buf][(nt * 16 + fr) * 32 + quad * 8]);
            bf16x8 bk1 = *reinterpret_cast<const bf16x8*>(&Ks[buf][2048 + (nt * 16 + fr) * 32 + quad * 8]);
            sa[nt] = __builtin_amdgcn_mfma_f32_16x16x32_bf16(aq0, bk0, zz, 0, 0, 0);
            sa[nt] = __builtin_amdgcn_mfma_f32_16x16x32_bf16(aq1, bk1, sa[nt], 0, 0, 0);
        }
        // scale + causal mask (C-layout: row=quad*4+r, col=fr)
        const bool diag = (kt == qtile);
#pragma unroll
        for (int nt = 0; nt < 4; ++nt)
#pragma unroll
            for (int r = 0; r < 4; ++r) {
                float s = sa[nt][r] * 0.125f;
                if (diag && (nt * 16 + fr > w * 16 + quad * 4 + r)) s = -__builtin_inff();
                sa[nt][r] = s;
            }
        // online softmax; P -> Ps (bf16, same-wave rows)
#pragma unroll
        for (int r = 0; r < 4; ++r) {
            float mt = fmaxf(fmaxf(sa[0][r], sa[1][r]), fmaxf(sa[2][r], sa[3][r]));
            mt = fmaxf(mt, __shfl_xor(mt, 1));
            mt = fmaxf(mt, __shfl_xor(mt, 2));
            mt = fmaxf(mt, __shfl_xor(mt, 4));
            mt = fmaxf(mt, __shfl_xor(mt, 8));
            const float mn = fmaxf(m_[r], mt);
            const float al = __expf(m_[r] - mn);
            m_[r] = mn;
            float rs = 0.f;
            const int prow = (w * 16 + quad * 4 + r) * 40 + fr;
#pragma unroll
            for (int nt = 0; nt < 4; ++nt) {
                const float p = __expf(sa[nt][r] - mn);
                rs += p;
                Ps[(nt >> 1) * 2560 + prow + (nt & 1) * 16] = f2b(p);
                oacc[nt][r] *= al;
            }
            rs += __shfl_xor(rs, 1);
            rs += __shfl_xor(rs, 2);
            rs += __shfl_xor(rs, 4);
            rs += __shfl_xor(rs, 8);
            l_[r] = l_[r] * al + rs;
        }
        // PV
        bf16x8 ap0 = *reinterpret_cast<const bf16x8*>(&Ps[(w * 16 + fr) * 40 + quad * 8]);
        bf16x8 ap1 = *reinterpret_cast<const bf16x8*>(&Ps[2560 + (w * 16 + fr) * 40 + quad * 8]);
#pragma unroll
        for (int nt = 0; nt < 4; ++nt) {
            bf16x8 bv0 = *reinterpret_cast<const bf16x8*>(&Vt[buf][(nt * 16 + fr) * 40 + quad * 8]);
            bf16x8 bv1 = *reinterpret_cast<const bf16x8*>(&Vt[buf][2560 + (nt * 16 + fr) * 40 + quad * 8]);
            oacc[nt] = __builtin_amdgcn_mfma_f32_16x16x32_bf16(ap0, bv0, oacc[nt], 0, 0, 0);
            oacc[nt] = __builtin_amdgcn_mfma_f32_16x16x32_bf16(ap1, bv1, oacc[nt], 0, 0, 0);
        }
        // phase end: epilogue + reset
        if (j == qA || j == total - 1) {
#pragma unroll
            for (int r = 0; r < 4; ++r) {
                const float inv = 1.0f / l_[r];
                const int q = qtile * 64 + w * 16 + quad * 4 + r;
#pragma unroll
                for (int nt = 0; nt < 4; ++nt)
                    AO[(((size_t)b * SEQ + q) * NH + h) * HD + nt * 16 + fr] = f2b(oacc[nt][r] * inv);
            }
            if (j == qA) {
#pragma unroll
                for (int r = 0; r < 4; ++r) { m_[r] = -__builtin_inff(); l_[r] = 0.f; }
#pragma unroll
                for (int nt = 0; nt < 4; ++nt) oacc[nt] = zz;
            }
        }
    }
}

extern "C" void kernel_launch(void* const* d_in, const int* in_sizes, int n_in,
                              void* d_out, int out_size, void* d_ws, size_t ws_size,
                              hipStream_t stream) {
    (void)in_sizes; (void)n_in; (void)out_size; (void)ws_size;
    const void* x  = d_in[0];
    const void* Wq = d_in[1];
    const void* Wk = d_in[2];
    const void* Wv = d_in[3];
    const void* Wo = d_in[4];

    char* ws = (char*)d_ws;
    const size_t MB = 1024 * 1024;
    int* flag = (int*)ws;                                   // 64 B
    u16* xb   = (u16*)(ws + 64);                            // 8 MB (reused as AO)
    u16* Wqkv = (u16*)(ws + 64 + 8 * MB);                   // 6 MB
    u16* Wob  = (u16*)(ws + 64 + 14 * MB);                  // 2 MB
    u16* Qb   = (u16*)(ws + 64 + 16 * MB);                  // 8 MB
    u16* Kb   = (u16*)(ws + 64 + 24 * MB);                  // 8 MB
    u16* Vb   = (u16*)(ws + 64 + 32 * MB);                  // 8 MB (total 40 MB + 64)
    u16* AO   = xb;                                         // x dead after QKV GEMM

    detect_dtype_54571854463007<<<1, 256, 0, stream>>>((const u16*)x, flag);

    const int NX = NB * SEQ * EMB;
    const int NW = EMB * EMB;
    convert_54571854463007<<<NX / 2048, 256, 0, stream>>>(x,  xb,            flag, NX);
    convert_54571854463007<<<NW / 2048, 256, 0, stream>>>(Wq, Wqkv,          flag, NW);
    convert_54571854463007<<<NW / 2048, 256, 0, stream>>>(Wk, Wqkv + NW,     flag, NW);
    convert_54571854463007<<<NW / 2048, 256, 0, stream>>>(Wv, Wqkv + 2 * NW, flag, NW);
    convert_54571854463007<<<NW / 2048, 256, 0, stream>>>(Wo, Wob,           flag, NW);

    const int M = NB * SEQ;
    gemm_mfma_54571854463007<1><<<dim3(3 * EMB / 128, M / 128), 256, 0, stream>>>(
        xb, Wqkv, Qb, flag, M, 3 * EMB, EMB);

    const int rope_threads = NB * NH * SEQ * 32;
    rope_54571854463007<<<rope_threads / 256, 256, 0, stream>>>(Qb, Kb);

    flash_54571854463007<<<dim3(16, NH, NB), 256, 0, stream>>>(Qb, Kb, Vb, AO);

    gemm_mfma_54571854463007<0><<<dim3(EMB / 128, M / 128), 256, 0, stream>>>(
        AO, Wob, d_out, flag, M, EMB, EMB);
}